// Round 1
// baseline (267.224 us; speedup 1.0000x reference)
//
#include <hip/hip_runtime.h>

#define SEQ 4096
#define EMB 768
#define NH 12
#define HD 64
#define LNEG -100000000.0f

typedef __attribute__((ext_vector_type(8))) short short8;
typedef __attribute__((ext_vector_type(4))) short short4v;
typedef __attribute__((ext_vector_type(4))) float f32x4;

__device__ inline unsigned short f2bf(float f) {
    unsigned int u = __float_as_uint(f);
    u += 0x7fffu + ((u >> 16) & 1u);
    return (unsigned short)(u >> 16);
}

// ---------------- Projection: q,k,v = hid @ W + b (q scaled by 1/8) ----------------
// grid (32, 6, 3), block 256.  Tile 128x128, 4 waves of 64x64 each.
__global__ __launch_bounds__(256) void proj_kernel(
    const float* __restrict__ hid,
    const float* __restrict__ Wq, const float* __restrict__ bq,
    const float* __restrict__ Wk, const float* __restrict__ bk,
    const float* __restrict__ Wv, const float* __restrict__ bv,
    unsigned short* __restrict__ q_ws,   // [H][S][D] bf16
    unsigned short* __restrict__ k_ws,   // [H][S][D] bf16
    unsigned short* __restrict__ v_ws)   // [H][D][S] bf16 (transposed per head)
{
    const int m0 = blockIdx.x * 128;
    const int n0 = blockIdx.y * 128;
    const int mat = blockIdx.z;
    const float* Wm = (mat == 0) ? Wq : (mat == 1 ? Wk : Wv);
    const float* bm = (mat == 0) ? bq : (mat == 1 ? bk : bv);

    __shared__ unsigned short Alds[128 * 40];  // [m][k], stride 40 (pad) bf16
    __shared__ unsigned short Blds[128 * 40];  // [n][k], stride 40 bf16

    const int t = threadIdx.x;
    const int wave = t >> 6, lane = t & 63;
    const int quad = lane >> 4, l16 = lane & 15;
    const int wr = wave >> 1, wc = wave & 1;

    const f32x4 zero = {0.f, 0.f, 0.f, 0.f};
    f32x4 acc[4][4];
    #pragma unroll
    for (int i = 0; i < 4; i++)
        #pragma unroll
        for (int j = 0; j < 4; j++) acc[i][j] = zero;

    for (int k0 = 0; k0 < EMB; k0 += 32) {
        // A tile: 128 rows x 32 k, 512 segments of 8 floats
        #pragma unroll
        for (int p = 0; p < 2; p++) {
            int id = t + p * 256;
            int row = id >> 2, sc = (id & 3) * 8;
            const float* gp = hid + (m0 + row) * EMB + k0 + sc;
            f32x4 v0 = *(const f32x4*)gp;
            f32x4 v1 = *(const f32x4*)(gp + 4);
            short4v o0, o1;
            o0[0] = (short)f2bf(v0[0]); o0[1] = (short)f2bf(v0[1]);
            o0[2] = (short)f2bf(v0[2]); o0[3] = (short)f2bf(v0[3]);
            o1[0] = (short)f2bf(v1[0]); o1[1] = (short)f2bf(v1[1]);
            o1[2] = (short)f2bf(v1[2]); o1[3] = (short)f2bf(v1[3]);
            unsigned short* lp = Alds + row * 40 + sc;
            *(short4v*)lp = o0;
            *(short4v*)(lp + 4) = o1;
        }
        // B tile: 32 k-rows x 128 n, stored transposed [n][k]
        #pragma unroll
        for (int p = 0; p < 2; p++) {
            int id = t + p * 256;
            int kr = id >> 4, sc = (id & 15) * 8;
            const float* gp = Wm + (k0 + kr) * EMB + n0 + sc;
            f32x4 v0 = *(const f32x4*)gp;
            f32x4 v1 = *(const f32x4*)(gp + 4);
            #pragma unroll
            for (int x = 0; x < 4; x++) {
                Blds[(sc + x) * 40 + kr]     = f2bf(v0[x]);
                Blds[(sc + 4 + x) * 40 + kr] = f2bf(v1[x]);
            }
        }
        __syncthreads();

        short8 af[4], bfv[4];
        #pragma unroll
        for (int rt = 0; rt < 4; rt++)
            af[rt] = *(const short8*)(Alds + (wr * 64 + rt * 16 + l16) * 40 + quad * 8);
        #pragma unroll
        for (int ct = 0; ct < 4; ct++)
            bfv[ct] = *(const short8*)(Blds + (wc * 64 + ct * 16 + l16) * 40 + quad * 8);
        #pragma unroll
        for (int rt = 0; rt < 4; rt++)
            #pragma unroll
            for (int ct = 0; ct < 4; ct++)
                acc[rt][ct] = __builtin_amdgcn_mfma_f32_16x16x32_bf16(af[rt], bfv[ct], acc[rt][ct], 0, 0, 0);
        __syncthreads();
    }

    const float scale = (mat == 0) ? 0.125f : 1.0f;
    #pragma unroll
    for (int ct = 0; ct < 4; ct++) {
        int n = n0 + wc * 64 + ct * 16 + l16;
        int head = n >> 6, dd = n & 63;
        float bias = bm[n];
        #pragma unroll
        for (int rt = 0; rt < 4; rt++) {
            int sb = m0 + wr * 64 + rt * 16 + quad * 4;
            if (mat == 2) {
                short4v pv;
                #pragma unroll
                for (int r = 0; r < 4; r++) pv[r] = (short)f2bf(acc[rt][ct][r] + bias);
                *(short4v*)(v_ws + head * (HD * SEQ) + dd * SEQ + sb) = pv;
            } else {
                unsigned short* dst = (mat == 0 ? q_ws : k_ws) + head * (SEQ * HD) + sb * HD + dd;
                #pragma unroll
                for (int r = 0; r < 4; r++)
                    dst[r * HD] = f2bf((acc[rt][ct][r] + bias) * scale);
            }
        }
    }
}

// ---------------- Banded attention ----------------
// grid (256 chunks, 12 heads), block 256 (4 waves). 16 query rows per WG,
// key window of 528 (+16 zero pad -> 544 = 17*32).
__global__ __launch_bounds__(256) void attn_kernel(
    const unsigned short* __restrict__ q_ws,
    const unsigned short* __restrict__ k_ws,
    const unsigned short* __restrict__ v_ws,
    const float* __restrict__ amask,
    const unsigned char* __restrict__ imask,
    float* __restrict__ out)
{
    const int c = blockIdx.x, h = blockIdx.y;
    const int i0 = c * 16;
    const int j0 = i0 - 256;
    const int t = threadIdx.x;
    const int wave = t >> 6, lane = t & 63;
    const int quad = lane >> 4, l16 = lane & 15;

    __shared__ float Slds[16 * 548];  // scores / probs, row stride 548 (16B-aligned rows)

    // Q fragments (all waves hold the same 16 rows): A[m=l16][k=quad*8+j]
    const unsigned short* qbase = q_ws + h * (SEQ * HD) + (i0 + l16) * HD + quad * 8;
    short8 a0 = *(const short8*)qbase;
    short8 a1 = *(const short8*)(qbase + 32);

    // ---- QK^T: 33 column tiles of 16 keys ----
    const unsigned short* kh = k_ws + h * (SEQ * HD);
    for (int tile = wave; tile < 33; tile += 4) {
        int j = j0 + tile * 16 + l16;
        int jc = min(max(j, 0), SEQ - 1);
        const unsigned short* kb = kh + jc * HD + quad * 8;
        short8 b0 = *(const short8*)kb;
        short8 b1 = *(const short8*)(kb + 32);
        f32x4 s = {0.f, 0.f, 0.f, 0.f};
        s = __builtin_amdgcn_mfma_f32_16x16x32_bf16(a0, b0, s, 0, 0, 0);
        s = __builtin_amdgcn_mfma_f32_16x16x32_bf16(a1, b1, s, 0, 0, 0);
        #pragma unroll
        for (int r = 0; r < 4; r++)
            Slds[(quad * 4 + r) * 548 + tile * 16 + l16] = s[r];
    }
    __syncthreads();

    // ---- softmax: 16 threads per row (rows of a wave stay inside the wave) ----
    {
        const int r = t >> 4, t16 = t & 15;
        const int i = i0 + r;
        float* Srow = Slds + r * 548;
        float mx = -1e30f;
        for (int cc = t16; cc < 544; cc += 16) {
            int j = j0 + cc;
            bool valid = (cc >= r) && (cc <= r + 512) && (j >= 0) && (j < SEQ);
            float sv = -1e30f;
            if (valid) {
                sv = Srow[cc];
                if (amask[j] != 0.0f) sv += LNEG;
            }
            mx = fmaxf(mx, sv);
        }
        #pragma unroll
        for (int off = 1; off < 16; off <<= 1)
            mx = fmaxf(mx, __shfl_xor(mx, off, 16));
        float sum = 0.f;
        for (int cc = t16; cc < 544; cc += 16) {
            int j = j0 + cc;
            bool valid = (cc >= r) && (cc <= r + 512) && (j >= 0) && (j < SEQ);
            float e = 0.f;
            if (valid) {
                float sv = Srow[cc];
                if (amask[j] != 0.0f) sv += LNEG;
                e = __expf(sv - mx);
            }
            Srow[cc] = e;
            sum += e;
        }
        #pragma unroll
        for (int off = 1; off < 16; off <<= 1)
            sum += __shfl_xor(sum, off, 16);
        float rinv = (imask[i] != 0) ? 0.f : (1.f / sum);
        for (int cc = t16; cc < 544; cc += 16)
            Srow[cc] *= rinv;
    }
    __syncthreads();

    // ---- PV: each wave one 16-wide d tile, K-loop over 544 keys ----
    f32x4 o = {0.f, 0.f, 0.f, 0.f};
    const int dd = wave * 16 + l16;
    const unsigned short* vbase = v_ws + h * (HD * SEQ) + dd * SEQ;
    for (int kk = 0; kk < 17; kk++) {
        const float* pp = Slds + l16 * 548 + kk * 32 + quad * 8;
        f32x4 p0 = *(const f32x4*)pp;
        f32x4 p1 = *(const f32x4*)(pp + 4);
        short8 af;
        af[0] = (short)f2bf(p0[0]); af[1] = (short)f2bf(p0[1]);
        af[2] = (short)f2bf(p0[2]); af[3] = (short)f2bf(p0[3]);
        af[4] = (short)f2bf(p1[0]); af[5] = (short)f2bf(p1[1]);
        af[6] = (short)f2bf(p1[2]); af[7] = (short)f2bf(p1[3]);
        int jb = j0 + kk * 32 + quad * 8;   // 8-aligned groups: fully valid or fully masked
        jb = min(max(jb, 0), SEQ - 8);
        short8 vb = *(const short8*)(vbase + jb);
        o = __builtin_amdgcn_mfma_f32_16x16x32_bf16(af, vb, o, 0, 0, 0);
    }
    float* obase = out + (i0 + quad * 4) * EMB + h * HD + dd;
    #pragma unroll
    for (int r = 0; r < 4; r++)
        obase[r * EMB] = o[r];
}

extern "C" void kernel_launch(void* const* d_in, const int* in_sizes, int n_in,
                              void* d_out, int out_size, void* d_ws, size_t ws_size,
                              hipStream_t stream) {
    (void)in_sizes; (void)n_in; (void)out_size; (void)ws_size;
    const float* hid = (const float*)d_in[0];
    const float* am  = (const float*)d_in[1];
    const unsigned char* im = (const unsigned char*)d_in[2];
    const float* Wq = (const float*)d_in[3];
    const float* bq = (const float*)d_in[4];
    const float* Wk = (const float*)d_in[5];
    const float* bk = (const float*)d_in[6];
    const float* Wv = (const float*)d_in[7];
    const float* bv = (const float*)d_in[8];
    float* out = (float*)d_out;

    unsigned short* ws = (unsigned short*)d_ws;
    unsigned short* q_ws = ws;
    unsigned short* k_ws = ws + (size_t)NH * SEQ * HD;
    unsigned short* v_ws = ws + 2 * (size_t)NH * SEQ * HD;

    dim3 g1(32, 6, 3);
    proj_kernel<<<g1, 256, 0, stream>>>(hid, Wq, bq, Wk, bk, Wv, bv, q_ws, k_ws, v_ws);
    dim3 g2(256, NH);
    attn_kernel<<<g2, 256, 0, stream>>>(q_ws, k_ws, v_ws, am, im, out);
}

// Round 2
// 216.611 us; speedup vs baseline: 1.2337x; 1.2337x over previous
//
#include <hip/hip_runtime.h>

#define SEQ 4096
#define EMB 768
#define NH 12
#define HD 64
#define KDIM 768
#define NTOT 2304
#define LNEG -100000000.0f

typedef __attribute__((ext_vector_type(8))) short short8;
typedef __attribute__((ext_vector_type(4))) short short4v;
typedef __attribute__((ext_vector_type(4))) float f32x4;

__device__ inline unsigned short f2bf(float f) {
    unsigned int u = __float_as_uint(f);
    u += 0x7fffu + ((u >> 16) & 1u);
    return (unsigned short)(u >> 16);
}

__device__ inline void gload_lds16(const unsigned short* g, unsigned short* l) {
    __builtin_amdgcn_global_load_lds(
        (const __attribute__((address_space(1))) void*)g,
        (__attribute__((address_space(3))) void*)l, 16, 0, 0);
}

// ---------------- Prep: hid -> bf16, W -> W^T bf16 (q-scale folded into Wq) ----------------
// grid (12, 12, 4), block 256. z<3: 64x64 transpose tiles of W; z==3: hid convert.
__global__ __launch_bounds__(256) void prep_kernel(
    const float* __restrict__ hid,
    const float* __restrict__ Wq, const float* __restrict__ Wk, const float* __restrict__ Wv,
    unsigned short* __restrict__ hidb,   // [4096][768] bf16
    unsigned short* __restrict__ Wt)     // [2304][768] bf16, [n][k]
{
    const int t = threadIdx.x;
    if (blockIdx.z == 3) {
        int vid = (blockIdx.y * 12 + blockIdx.x) * 256 + t;
        const int stride = 144 * 256;
        const int nch = SEQ * EMB / 4;
        for (int c = vid; c < nch; c += stride) {
            f32x4 v = ((const f32x4*)hid)[c];
            short4v o;
            #pragma unroll
            for (int x = 0; x < 4; x++) o[x] = (short)f2bf(v[x]);
            ((short4v*)hidb)[c] = o;
        }
        return;
    }
    const int mat = blockIdx.z;
    const float* Wm = (mat == 0) ? Wq : (mat == 1 ? Wk : Wv);
    const float scale = (mat == 0) ? 0.125f : 1.0f;
    const int k0 = blockIdx.x * 64;
    const int n0 = blockIdx.y * 64;
    __shared__ unsigned short Lt[64 * 80];
    #pragma unroll
    for (int i = 0; i < 4; i++) {
        int row = i * 16 + (t >> 4);   // k-local
        int col = (t & 15) * 4;        // n-local
        f32x4 v = *(const f32x4*)(Wm + (size_t)(k0 + row) * EMB + n0 + col);
        #pragma unroll
        for (int x = 0; x < 4; x++)
            Lt[(col + x) * 80 + row] = f2bf(v[x] * scale);
    }
    __syncthreads();
    #pragma unroll
    for (int j = 0; j < 2; j++) {
        int idx = j * 256 + t;
        int nr = idx >> 3;
        int kc = (idx & 7) * 8;
        short8 o = *(const short8*)(Lt + nr * 80 + kc);
        *(short8*)(Wt + (size_t)(mat * 768 + n0 + nr) * KDIM + k0 + kc) = o;
    }
}

// ---------------- GEMM: [4096][768]bf16 @ [2304][768]^T bf16 -> q,k,v ----------------
// grid (32, 18), block 256, 4 waves 2x2 of 64x64. BK=64, global_load_lds(16B), xor-swizzle.
__global__ __launch_bounds__(256) void gemm_kernel(
    const unsigned short* __restrict__ hidb,
    const unsigned short* __restrict__ Wt,
    const float* __restrict__ bq, const float* __restrict__ bk, const float* __restrict__ bv,
    unsigned short* __restrict__ q_ws,   // [H][S][D] bf16
    unsigned short* __restrict__ k_ws,   // [H][S][D] bf16
    unsigned short* __restrict__ v_ws)   // [H][D][S] bf16
{
    const int m0 = blockIdx.x * 128;
    const int n0 = blockIdx.y * 128;
    __shared__ unsigned short Al[128 * 64];
    __shared__ unsigned short Bl[128 * 64];
    const int t = threadIdx.x;
    const int wave = t >> 6, lane = t & 63;
    const int quad = lane >> 4, l16 = lane & 15;
    const int wr = wave >> 1, wc = wave & 1;

    const f32x4 zero = {0.f, 0.f, 0.f, 0.f};
    f32x4 acc[4][4];
    #pragma unroll
    for (int i = 0; i < 4; i++)
        #pragma unroll
        for (int j = 0; j < 4; j++) acc[i][j] = zero;

    for (int k0 = 0; k0 < KDIM; k0 += 64) {
        #pragma unroll
        for (int i = 0; i < 4; i++) {
            int c = (wave * 4 + i) * 64 + lane;            // chunk id 0..1023
            int row = c >> 3;
            int kc = ((c & 7) ^ (row & 7)) * 8;            // swizzled k-offset (elems)
            gload_lds16(hidb + (size_t)(m0 + row) * KDIM + k0 + kc, Al + (wave * 4 + i) * 512);
            gload_lds16(Wt   + (size_t)(n0 + row) * KDIM + k0 + kc, Bl + (wave * 4 + i) * 512);
        }
        __syncthreads();

        short8 af[2][4], bfr[2][4];
        #pragma unroll
        for (int rt = 0; rt < 4; rt++) {
            int rowA = wr * 64 + rt * 16 + l16;
            int rowB = wc * 64 + rt * 16 + l16;
            #pragma unroll
            for (int s = 0; s < 2; s++) {
                af[s][rt]  = *(const short8*)(Al + rowA * 64 + (((s << 2) | quad) ^ (rowA & 7)) * 8);
                bfr[s][rt] = *(const short8*)(Bl + rowB * 64 + (((s << 2) | quad) ^ (rowB & 7)) * 8);
            }
        }
        #pragma unroll
        for (int s = 0; s < 2; s++)
            #pragma unroll
            for (int rt = 0; rt < 4; rt++)
                #pragma unroll
                for (int ct = 0; ct < 4; ct++)
                    acc[rt][ct] = __builtin_amdgcn_mfma_f32_16x16x32_bf16(af[s][rt], bfr[s][ct], acc[rt][ct], 0, 0, 0);
        __syncthreads();
    }

    const int mat = blockIdx.y / 6;                 // 128-col blocks never straddle a matrix
    const float* bm = (mat == 0) ? bq : (mat == 1 ? bk : bv);
    const float bscale = (mat == 0) ? 0.125f : 1.0f;
    #pragma unroll
    for (int ct = 0; ct < 4; ct++) {
        int ncol = n0 + wc * 64 + ct * 16 + l16;
        int within = ncol - mat * 768;
        int head = within >> 6, dd = within & 63;
        float bias = bm[within] * bscale;
        #pragma unroll
        for (int rt = 0; rt < 4; rt++) {
            int sb = m0 + wr * 64 + rt * 16 + quad * 4;
            if (mat == 2) {
                short4v pv;
                #pragma unroll
                for (int r = 0; r < 4; r++) pv[r] = (short)f2bf(acc[rt][ct][r] + bias);
                *(short4v*)(v_ws + head * (HD * SEQ) + dd * SEQ + sb) = pv;
            } else {
                unsigned short* dst = (mat == 0 ? q_ws : k_ws) + head * (SEQ * HD) + sb * HD + dd;
                #pragma unroll
                for (int r = 0; r < 4; r++)
                    dst[r * HD] = f2bf(acc[rt][ct][r] + bias);
            }
        }
    }
}

// ---------------- Banded attention ----------------
// grid (256 chunks, 12 heads), block 256 (4 waves). 16 query rows / WG, window 528 (+16 pad).
__global__ __launch_bounds__(256) void attn_kernel(
    const unsigned short* __restrict__ q_ws,
    const unsigned short* __restrict__ k_ws,
    const unsigned short* __restrict__ v_ws,
    const float* __restrict__ amask,
    const unsigned char* __restrict__ imask,
    float* __restrict__ out)
{
    const int c = blockIdx.x, h = blockIdx.y;
    const int i0 = c * 16;
    const int j0 = i0 - 256;
    const int t = threadIdx.x;
    const int wave = t >> 6, lane = t & 63;
    const int quad = lane >> 4, l16 = lane & 15;

    __shared__ float Slds[16 * 544];         // scores (f32), row stride 544
    __shared__ unsigned short Pb[16 * 544];  // probs (bf16), A-fragment-ready
    __shared__ float fm[544];                // per-key mask term (j-validity + attention_mask)

    // Q fragments (all waves hold the same 16 rows)
    const unsigned short* qbase = q_ws + h * (SEQ * HD) + (i0 + l16) * HD + quad * 8;
    short8 a0 = *(const short8*)qbase;
    short8 a1 = *(const short8*)(qbase + 32);

    // precompute mask term; zero tail score cols (528..543)
    for (int cc = t; cc < 544; cc += 256) {
        int j = j0 + cc;
        fm[cc] = (j < 0 || j >= SEQ) ? -1e30f : ((amask[j] != 0.0f) ? LNEG : 0.0f);
    }
    Slds[(t >> 4) * 544 + 528 + (t & 15)] = 0.f;

    // ---- QK^T: 33 column tiles of 16 keys ----
    const unsigned short* kh = k_ws + h * (SEQ * HD);
    for (int tile = wave; tile < 33; tile += 4) {
        int j = j0 + tile * 16 + l16;
        int jc = min(max(j, 0), SEQ - 1);
        const unsigned short* kb = kh + jc * HD + quad * 8;
        short8 b0 = *(const short8*)kb;
        short8 b1 = *(const short8*)(kb + 32);
        f32x4 s = {0.f, 0.f, 0.f, 0.f};
        s = __builtin_amdgcn_mfma_f32_16x16x32_bf16(a0, b0, s, 0, 0, 0);
        s = __builtin_amdgcn_mfma_f32_16x16x32_bf16(a1, b1, s, 0, 0, 0);
        #pragma unroll
        for (int r = 0; r < 4; r++)
            Slds[(quad * 4 + r) * 544 + tile * 16 + l16] = s[r];
    }
    __syncthreads();

    // ---- softmax: 16 threads per row ----
    {
        const int r = t >> 4, t16 = t & 15;
        float* Srow = Slds + r * 544;
        float mx = -1e30f;
        for (int cc = t16; cc < 544; cc += 16) {
            float sv = ((unsigned)(cc - r) <= 512u) ? (Srow[cc] + fm[cc]) : -1e30f;
            mx = fmaxf(mx, sv);
        }
        #pragma unroll
        for (int off = 1; off < 16; off <<= 1)
            mx = fmaxf(mx, __shfl_xor(mx, off, 16));
        float sum = 0.f;
        for (int cc = t16; cc < 544; cc += 16) {
            float sv = ((unsigned)(cc - r) <= 512u) ? (Srow[cc] + fm[cc]) : -1e30f;
            float e = __expf(sv - mx);
            Srow[cc] = e;
            sum += e;
        }
        #pragma unroll
        for (int off = 1; off < 16; off <<= 1)
            sum += __shfl_xor(sum, off, 16);
        float rinv = (imask[i0 + r] != 0) ? 0.f : (1.f / sum);
        for (int cc = t16; cc < 544; cc += 16)
            Pb[r * 544 + cc] = f2bf(Srow[cc] * rinv);
    }
    __syncthreads();

    // ---- PV: each wave one 16-wide d tile, 17 K-groups of 32 ----
    f32x4 o = {0.f, 0.f, 0.f, 0.f};
    const int dd = wave * 16 + l16;
    const unsigned short* vbase = v_ws + h * (HD * SEQ) + dd * SEQ;
    for (int kk = 0; kk < 17; kk++) {
        short8 af = *(const short8*)(Pb + l16 * 544 + kk * 32 + quad * 8);
        int jb = j0 + kk * 32 + quad * 8;     // 8-aligned: fully valid or fully masked
        jb = min(max(jb, 0), SEQ - 8);
        short8 vb = *(const short8*)(vbase + jb);
        o = __builtin_amdgcn_mfma_f32_16x16x32_bf16(af, vb, o, 0, 0, 0);
    }
    float* obase = out + (size_t)(i0 + quad * 4) * EMB + h * HD + dd;
    #pragma unroll
    for (int r = 0; r < 4; r++)
        obase[r * EMB] = o[r];
}

extern "C" void kernel_launch(void* const* d_in, const int* in_sizes, int n_in,
                              void* d_out, int out_size, void* d_ws, size_t ws_size,
                              hipStream_t stream) {
    (void)in_sizes; (void)n_in; (void)out_size; (void)ws_size;
    const float* hid = (const float*)d_in[0];
    const float* am  = (const float*)d_in[1];
    const unsigned char* im = (const unsigned char*)d_in[2];
    const float* Wq = (const float*)d_in[3];
    const float* bq = (const float*)d_in[4];
    const float* Wk = (const float*)d_in[5];
    const float* bk = (const float*)d_in[6];
    const float* Wv = (const float*)d_in[7];
    const float* bv = (const float*)d_in[8];
    float* out = (float*)d_out;

    // ws: q,k,v (bf16). d_out doubles as scratch for hidb+Wt (9.8 MB < 12.6 MB),
    // safe because attn overwrites d_out last and never reads it.
    unsigned short* ws = (unsigned short*)d_ws;
    unsigned short* q_ws = ws;
    unsigned short* k_ws = ws + (size_t)NH * SEQ * HD;
    unsigned short* v_ws = ws + 2 * (size_t)NH * SEQ * HD;
    unsigned short* hidb = (unsigned short*)d_out;
    unsigned short* Wt   = hidb + (size_t)SEQ * EMB;

    dim3 gp(12, 12, 4);
    prep_kernel<<<gp, 256, 0, stream>>>(hid, Wq, Wk, Wv, hidb, Wt);
    dim3 gg(32, 18);
    gemm_kernel<<<gg, 256, 0, stream>>>(hidb, Wt, bq, bk, bv, q_ws, k_ws, v_ws);
    dim3 ga(256, NH);
    attn_kernel<<<ga, 256, 0, stream>>>(q_ws, k_ws, v_ws, am, im, out);
}

// Round 3
// 179.796 us; speedup vs baseline: 1.4863x; 1.2048x over previous
//
#include <hip/hip_runtime.h>

#define SEQ 4096
#define EMB 768
#define NH 12
#define HD 64
#define KDIM 768
#define NTOT 2304
#define LNEG -100000000.0f
#define SSTR 548   // score row stride (f32); 548 % 32 == 4 -> bank-rotated rows

typedef __attribute__((ext_vector_type(8))) short short8;
typedef __attribute__((ext_vector_type(4))) short short4v;
typedef __attribute__((ext_vector_type(4))) float f32x4;

__device__ inline unsigned short f2bf(float f) {
    unsigned int u = __float_as_uint(f);
    u += 0x7fffu + ((u >> 16) & 1u);
    return (unsigned short)(u >> 16);
}

__device__ inline void gload_lds16(const unsigned short* g, unsigned short* l) {
    __builtin_amdgcn_global_load_lds(
        (const __attribute__((address_space(1))) void*)g,
        (__attribute__((address_space(3))) void*)l, 16, 0, 0);
}

// ---------------- Prep: hid -> bf16, W -> W^T bf16 (q-scale folded into Wq) ----------------
__global__ __launch_bounds__(256) void prep_kernel(
    const float* __restrict__ hid,
    const float* __restrict__ Wq, const float* __restrict__ Wk, const float* __restrict__ Wv,
    unsigned short* __restrict__ hidb,   // [4096][768] bf16
    unsigned short* __restrict__ Wt)     // [2304][768] bf16, [n][k]
{
    const int t = threadIdx.x;
    if (blockIdx.z == 3) {
        int vid = (blockIdx.y * 12 + blockIdx.x) * 256 + t;
        const int stride = 144 * 256;
        const int nch = SEQ * EMB / 4;
        for (int c = vid; c < nch; c += stride) {
            f32x4 v = ((const f32x4*)hid)[c];
            short4v o;
            #pragma unroll
            for (int x = 0; x < 4; x++) o[x] = (short)f2bf(v[x]);
            ((short4v*)hidb)[c] = o;
        }
        return;
    }
    const int mat = blockIdx.z;
    const float* Wm = (mat == 0) ? Wq : (mat == 1 ? Wk : Wv);
    const float scale = (mat == 0) ? 0.125f : 1.0f;
    const int k0 = blockIdx.x * 64;
    const int n0 = blockIdx.y * 64;
    __shared__ unsigned short Lt[64 * 80];
    #pragma unroll
    for (int i = 0; i < 4; i++) {
        int row = i * 16 + (t >> 4);
        int col = (t & 15) * 4;
        f32x4 v = *(const f32x4*)(Wm + (size_t)(k0 + row) * EMB + n0 + col);
        #pragma unroll
        for (int x = 0; x < 4; x++)
            Lt[(col + x) * 80 + row] = f2bf(v[x] * scale);
    }
    __syncthreads();
    #pragma unroll
    for (int j = 0; j < 2; j++) {
        int idx = j * 256 + t;
        int nr = idx >> 3;
        int kc = (idx & 7) * 8;
        short8 o = *(const short8*)(Lt + nr * 80 + kc);
        *(short8*)(Wt + (size_t)(mat * 768 + n0 + nr) * KDIM + k0 + kc) = o;
    }
}

// ---------------- GEMM: [4096][768]bf16 @ [2304][768]^T bf16 -> q,k,v ----------------
__global__ __launch_bounds__(256) void gemm_kernel(
    const unsigned short* __restrict__ hidb,
    const unsigned short* __restrict__ Wt,
    const float* __restrict__ bq, const float* __restrict__ bk, const float* __restrict__ bv,
    unsigned short* __restrict__ q_ws,   // [H][S][D] bf16
    unsigned short* __restrict__ k_ws,   // [H][S][D] bf16
    unsigned short* __restrict__ v_ws)   // [H][D][S] bf16
{
    const int m0 = blockIdx.x * 128;
    const int n0 = blockIdx.y * 128;
    __shared__ unsigned short Al[128 * 64];
    __shared__ unsigned short Bl[128 * 64];
    const int t = threadIdx.x;
    const int wave = t >> 6, lane = t & 63;
    const int quad = lane >> 4, l16 = lane & 15;
    const int wr = wave >> 1, wc = wave & 1;

    const f32x4 zero = {0.f, 0.f, 0.f, 0.f};
    f32x4 acc[4][4];
    #pragma unroll
    for (int i = 0; i < 4; i++)
        #pragma unroll
        for (int j = 0; j < 4; j++) acc[i][j] = zero;

    for (int k0 = 0; k0 < KDIM; k0 += 64) {
        #pragma unroll
        for (int i = 0; i < 4; i++) {
            int c = (wave * 4 + i) * 64 + lane;
            int row = c >> 3;
            int kc = ((c & 7) ^ (row & 7)) * 8;
            gload_lds16(hidb + (size_t)(m0 + row) * KDIM + k0 + kc, Al + (wave * 4 + i) * 512);
            gload_lds16(Wt   + (size_t)(n0 + row) * KDIM + k0 + kc, Bl + (wave * 4 + i) * 512);
        }
        __syncthreads();

        short8 af[2][4], bfr[2][4];
        #pragma unroll
        for (int rt = 0; rt < 4; rt++) {
            int rowA = wr * 64 + rt * 16 + l16;
            int rowB = wc * 64 + rt * 16 + l16;
            #pragma unroll
            for (int s = 0; s < 2; s++) {
                af[s][rt]  = *(const short8*)(Al + rowA * 64 + (((s << 2) | quad) ^ (rowA & 7)) * 8);
                bfr[s][rt] = *(const short8*)(Bl + rowB * 64 + (((s << 2) | quad) ^ (rowB & 7)) * 8);
            }
        }
        #pragma unroll
        for (int s = 0; s < 2; s++)
            #pragma unroll
            for (int rt = 0; rt < 4; rt++)
                #pragma unroll
                for (int ct = 0; ct < 4; ct++)
                    acc[rt][ct] = __builtin_amdgcn_mfma_f32_16x16x32_bf16(af[s][rt], bfr[s][ct], acc[rt][ct], 0, 0, 0);
        __syncthreads();
    }

    const int mat = blockIdx.y / 6;
    const float* bm = (mat == 0) ? bq : (mat == 1 ? bk : bv);
    const float bscale = (mat == 0) ? 0.125f : 1.0f;
    #pragma unroll
    for (int ct = 0; ct < 4; ct++) {
        int ncol = n0 + wc * 64 + ct * 16 + l16;
        int within = ncol - mat * 768;
        int head = within >> 6, dd = within & 63;
        float bias = bm[within] * bscale;
        #pragma unroll
        for (int rt = 0; rt < 4; rt++) {
            int sb = m0 + wr * 64 + rt * 16 + quad * 4;
            if (mat == 2) {
                short4v pv;
                #pragma unroll
                for (int r = 0; r < 4; r++) pv[r] = (short)f2bf(acc[rt][ct][r] + bias);
                *(short4v*)(v_ws + head * (HD * SEQ) + dd * SEQ + sb) = pv;
            } else {
                unsigned short* dst = (mat == 0 ? q_ws : k_ws) + head * (SEQ * HD) + sb * HD + dd;
                #pragma unroll
                for (int r = 0; r < 4; r++)
                    dst[r * HD] = f2bf(acc[rt][ct][r] + bias);
            }
        }
    }
}

// ---------------- Banded attention ----------------
// grid 3072 linear, remapped so each XCD owns contiguous (head,chunk) range.
// 16 query rows / WG, window 528 (+16 pad -> 544). Probs (bf16) alias the f32
// score/exp buffer in place: clobber frontier (2-byte writes at idx cc) stays
// strictly behind the 4-byte read frontier across iterations.
__global__ __launch_bounds__(256) void attn_kernel(
    const unsigned short* __restrict__ q_ws,
    const unsigned short* __restrict__ k_ws,
    const unsigned short* __restrict__ v_ws,
    const float* __restrict__ amask,
    const unsigned char* __restrict__ imask,
    float* __restrict__ out)
{
    const int lbid = blockIdx.x + gridDim.x * blockIdx.y;
    const int xcd = lbid & 7, slot = lbid >> 3;
    const int w = xcd * 384 + slot;            // 3072 work items, 384 contiguous per XCD
    const int h = w >> 8, c = w & 255;
    const int i0 = c * 16;
    const int j0 = i0 - 256;
    const int t = threadIdx.x;
    const int wave = t >> 6, lane = t & 63;
    const int quad = lane >> 4, l16 = lane & 15;

    __shared__ float Slds[16 * SSTR];          // scores -> exp -> (bf16 probs, aliased)
    __shared__ float fm[SSTR];                 // per-key mask term
    unsigned short* Pb = (unsigned short*)Slds; // row stride 2*SSTR shorts

    const unsigned short* qbase = q_ws + h * (SEQ * HD) + (i0 + l16) * HD + quad * 8;
    short8 a0 = *(const short8*)qbase;
    short8 a1 = *(const short8*)(qbase + 32);

    for (int cc = t; cc < 544; cc += 256) {
        int j = j0 + cc;
        fm[cc] = (j < 0 || j >= SEQ) ? -1e30f : ((amask[j] != 0.0f) ? LNEG : 0.0f);
    }
    Slds[(t >> 4) * SSTR + 528 + (t & 15)] = 0.f;   // zero pad cols 528..543

    // ---- QK^T: 33 column tiles of 16 keys ----
    const unsigned short* kh = k_ws + h * (SEQ * HD);
    for (int tile = wave; tile < 33; tile += 4) {
        int j = j0 + tile * 16 + l16;
        int jc = min(max(j, 0), SEQ - 1);
        const unsigned short* kb = kh + jc * HD + quad * 8;
        short8 b0 = *(const short8*)kb;
        short8 b1 = *(const short8*)(kb + 32);
        f32x4 s = {0.f, 0.f, 0.f, 0.f};
        s = __builtin_amdgcn_mfma_f32_16x16x32_bf16(a0, b0, s, 0, 0, 0);
        s = __builtin_amdgcn_mfma_f32_16x16x32_bf16(a1, b1, s, 0, 0, 0);
        #pragma unroll
        for (int r = 0; r < 4; r++)
            Slds[(quad * 4 + r) * SSTR + tile * 16 + l16] = s[r];
    }
    __syncthreads();

    // ---- softmax: 16 threads per row, f32x4 passes ----
    {
        const int r = t >> 4, t16 = t & 15;
        float* Srow = Slds + r * SSTR;
        float mx = -1e30f;
        #pragma unroll
        for (int it = 0; it < 9; it++) {
            int cc4 = it * 64 + t16 * 4;
            if (cc4 < 544) {
                f32x4 sv = *(const f32x4*)(Srow + cc4);
                f32x4 fv = *(const f32x4*)(fm + cc4);
                #pragma unroll
                for (int x = 0; x < 4; x++) {
                    float s = ((unsigned)(cc4 + x - r) <= 512u) ? (sv[x] + fv[x]) : -1e30f;
                    mx = fmaxf(mx, s);
                }
            }
        }
        #pragma unroll
        for (int off = 1; off < 16; off <<= 1)
            mx = fmaxf(mx, __shfl_xor(mx, off, 16));

        float sum = 0.f;
        #pragma unroll
        for (int it = 0; it < 9; it++) {
            int cc4 = it * 64 + t16 * 4;
            if (cc4 < 544) {
                f32x4 sv = *(const f32x4*)(Srow + cc4);
                f32x4 fv = *(const f32x4*)(fm + cc4);
                f32x4 ev;
                #pragma unroll
                for (int x = 0; x < 4; x++) {
                    bool valid = ((unsigned)(cc4 + x - r) <= 512u);
                    float e = valid ? __expf(sv[x] + fv[x] - mx) : 0.f;
                    ev[x] = e;
                    sum += e;
                }
                *(f32x4*)(Srow + cc4) = ev;
            }
        }
        #pragma unroll
        for (int off = 1; off < 16; off <<= 1)
            sum += __shfl_xor(sum, off, 16);
        float rinv = (imask[i0 + r] != 0) ? 0.f : (1.f / sum);

        // write bf16 probs over the same buffer (short idx cc at byte 2cc; the
        // f32 it clobbers, idx cc/2, was consumed in an earlier/equal iter)
        #pragma unroll
        for (int it = 0; it < 9; it++) {
            int cc4 = it * 64 + t16 * 4;
            if (cc4 < 544) {
                f32x4 ev = *(const f32x4*)(Srow + cc4);
                short4v pv;
                #pragma unroll
                for (int x = 0; x < 4; x++) pv[x] = (short)f2bf(ev[x] * rinv);
                *(short4v*)(Pb + r * (2 * SSTR) + cc4) = pv;
            }
        }
    }
    __syncthreads();

    // ---- PV: each wave one 16-wide d tile, 17 K-groups of 32 ----
    f32x4 o = {0.f, 0.f, 0.f, 0.f};
    const int dd = wave * 16 + l16;
    const unsigned short* vbase = v_ws + h * (HD * SEQ) + dd * SEQ;
    for (int kk = 0; kk < 17; kk++) {
        short8 af = *(const short8*)(Pb + l16 * (2 * SSTR) + kk * 32 + quad * 8);
        int jb = j0 + kk * 32 + quad * 8;
        jb = min(max(jb, 0), SEQ - 8);
        short8 vb = *(const short8*)(vbase + jb);
        o = __builtin_amdgcn_mfma_f32_16x16x32_bf16(af, vb, o, 0, 0, 0);
    }
    float* obase = out + (size_t)(i0 + quad * 4) * EMB + h * HD + dd;
    #pragma unroll
    for (int r = 0; r < 4; r++)
        obase[r * EMB] = o[r];
}

extern "C" void kernel_launch(void* const* d_in, const int* in_sizes, int n_in,
                              void* d_out, int out_size, void* d_ws, size_t ws_size,
                              hipStream_t stream) {
    (void)in_sizes; (void)n_in; (void)out_size; (void)ws_size;
    const float* hid = (const float*)d_in[0];
    const float* am  = (const float*)d_in[1];
    const unsigned char* im = (const unsigned char*)d_in[2];
    const float* Wq = (const float*)d_in[3];
    const float* bq = (const float*)d_in[4];
    const float* Wk = (const float*)d_in[5];
    const float* bk = (const float*)d_in[6];
    const float* Wv = (const float*)d_in[7];
    const float* bv = (const float*)d_in[8];
    float* out = (float*)d_out;

    unsigned short* ws = (unsigned short*)d_ws;
    unsigned short* q_ws = ws;
    unsigned short* k_ws = ws + (size_t)NH * SEQ * HD;
    unsigned short* v_ws = ws + 2 * (size_t)NH * SEQ * HD;
    unsigned short* hidb = (unsigned short*)d_out;   // d_out as scratch (attn overwrites last)
    unsigned short* Wt   = hidb + (size_t)SEQ * EMB;

    dim3 gp(12, 12, 4);
    prep_kernel<<<gp, 256, 0, stream>>>(hid, Wq, Wk, Wv, hidb, Wt);
    dim3 gg(32, 18);
    gemm_kernel<<<gg, 256, 0, stream>>>(hidb, Wt, bq, bk, bv, q_ws, k_ws, v_ws);
    dim3 ga(256, NH);
    attn_kernel<<<ga, 256, 0, stream>>>(q_ws, k_ws, v_ws, am, im, out);
}

// Round 4
// 170.345 us; speedup vs baseline: 1.5687x; 1.0555x over previous
//
#include <hip/hip_runtime.h>

#define SEQ 4096
#define EMB 768
#define NH 12
#define HD 64
#define KDIM 768
#define LNEG -100000000.0f
#define LOG2E 1.44269504f
#define PSTR 548   // Pb row stride (shorts): 274 words == 18 mod 32 -> conflict-free

typedef __attribute__((ext_vector_type(8))) short short8;
typedef __attribute__((ext_vector_type(4))) short short4v;
typedef __attribute__((ext_vector_type(4))) float f32x4;

__device__ inline unsigned short f2bf(float f) {
    unsigned int u = __float_as_uint(f);
    u += 0x7fffu + ((u >> 16) & 1u);
    return (unsigned short)(u >> 16);
}

__device__ inline void gload_lds16(const unsigned short* g, unsigned short* l) {
    __builtin_amdgcn_global_load_lds(
        (const __attribute__((address_space(1))) void*)g,
        (__attribute__((address_space(3))) void*)l, 16, 0, 0);
}

// ---------------- Prep: hid -> bf16, W -> W^T bf16 (q-scale*log2e folded into Wq) ----------------
__global__ __launch_bounds__(256) void prep_kernel(
    const float* __restrict__ hid,
    const float* __restrict__ Wq, const float* __restrict__ Wk, const float* __restrict__ Wv,
    unsigned short* __restrict__ hidb,   // [4096][768] bf16
    unsigned short* __restrict__ Wt)     // [2304][768] bf16, [n][k]
{
    const int t = threadIdx.x;
    if (blockIdx.z == 3) {
        int vid = (blockIdx.y * 12 + blockIdx.x) * 256 + t;
        const int stride = 144 * 256;
        const int nch = SEQ * EMB / 4;
        for (int c = vid; c < nch; c += stride) {
            f32x4 v = ((const f32x4*)hid)[c];
            short4v o;
            #pragma unroll
            for (int x = 0; x < 4; x++) o[x] = (short)f2bf(v[x]);
            ((short4v*)hidb)[c] = o;
        }
        return;
    }
    const int mat = blockIdx.z;
    const float* Wm = (mat == 0) ? Wq : (mat == 1 ? Wk : Wv);
    const float scale = (mat == 0) ? 0.125f * LOG2E : 1.0f;
    const int k0 = blockIdx.x * 64;
    const int n0 = blockIdx.y * 64;
    __shared__ unsigned short Lt[64 * 82];   // stride 82: write banks 2-way, not 16-way
    #pragma unroll
    for (int i = 0; i < 4; i++) {
        int row = i * 16 + (t >> 4);
        int col = (t & 15) * 4;
        f32x4 v = *(const f32x4*)(Wm + (size_t)(k0 + row) * EMB + n0 + col);
        #pragma unroll
        for (int x = 0; x < 4; x++)
            Lt[(col + x) * 82 + row] = f2bf(v[x] * scale);
    }
    __syncthreads();
    #pragma unroll
    for (int j = 0; j < 2; j++) {
        int idx = j * 256 + t;
        int nr = idx >> 3;
        int kc = (idx & 7) * 8;
        short8 o = *(const short8*)(Lt + nr * 82 + kc);
        *(short8*)(Wt + (size_t)(mat * 768 + n0 + nr) * KDIM + k0 + kc) = o;
    }
}

// ---------------- GEMM: 64x128 tiles, grid (64,18)=1152 WGs (4.5/CU) ----------------
__global__ __launch_bounds__(256) void gemm_kernel(
    const unsigned short* __restrict__ hidb,
    const unsigned short* __restrict__ Wt,
    const float* __restrict__ bq, const float* __restrict__ bk, const float* __restrict__ bv,
    unsigned short* __restrict__ q_ws,   // [H][S][D] bf16
    unsigned short* __restrict__ k_ws,   // [H][S][D] bf16
    unsigned short* __restrict__ v_ws)   // [H][D][S] bf16
{
    const int m0 = blockIdx.x * 64;
    const int n0 = blockIdx.y * 128;
    __shared__ unsigned short Al[64 * 64];    // 8 KB
    __shared__ unsigned short Bl[128 * 64];   // 16 KB
    const int t = threadIdx.x;
    const int wave = t >> 6, lane = t & 63;
    const int quad = lane >> 4, l16 = lane & 15;

    const f32x4 zero = {0.f, 0.f, 0.f, 0.f};
    f32x4 acc[4][2];
    #pragma unroll
    for (int i = 0; i < 4; i++)
        #pragma unroll
        for (int j = 0; j < 2; j++) acc[i][j] = zero;

    for (int k0 = 0; k0 < KDIM; k0 += 64) {
        #pragma unroll
        for (int i = 0; i < 2; i++) {
            int c = (wave * 2 + i) * 64 + lane;
            int row = c >> 3;
            int kc = ((c & 7) ^ (row & 7)) * 8;
            gload_lds16(hidb + (size_t)(m0 + row) * KDIM + k0 + kc, Al + (wave * 2 + i) * 512);
        }
        #pragma unroll
        for (int i = 0; i < 4; i++) {
            int c = (wave * 4 + i) * 64 + lane;
            int row = c >> 3;
            int kc = ((c & 7) ^ (row & 7)) * 8;
            gload_lds16(Wt + (size_t)(n0 + row) * KDIM + k0 + kc, Bl + (wave * 4 + i) * 512);
        }
        __syncthreads();

        short8 af[2][4], bfr[2][2];
        #pragma unroll
        for (int rt = 0; rt < 4; rt++) {
            int rowA = rt * 16 + l16;
            #pragma unroll
            for (int s = 0; s < 2; s++)
                af[s][rt] = *(const short8*)(Al + rowA * 64 + (((s << 2) | quad) ^ (rowA & 7)) * 8);
        }
        #pragma unroll
        for (int ct = 0; ct < 2; ct++) {
            int rowB = wave * 32 + ct * 16 + l16;
            #pragma unroll
            for (int s = 0; s < 2; s++)
                bfr[s][ct] = *(const short8*)(Bl + rowB * 64 + (((s << 2) | quad) ^ (rowB & 7)) * 8);
        }
        #pragma unroll
        for (int s = 0; s < 2; s++)
            #pragma unroll
            for (int rt = 0; rt < 4; rt++)
                #pragma unroll
                for (int ct = 0; ct < 2; ct++)
                    acc[rt][ct] = __builtin_amdgcn_mfma_f32_16x16x32_bf16(af[s][rt], bfr[s][ct], acc[rt][ct], 0, 0, 0);
        __syncthreads();
    }

    const int mat = blockIdx.y / 6;
    const float* bm = (mat == 0) ? bq : (mat == 1 ? bk : bv);
    const float bscale = (mat == 0) ? 0.125f * LOG2E : 1.0f;
    #pragma unroll
    for (int ct = 0; ct < 2; ct++) {
        int ncol = n0 + wave * 32 + ct * 16 + l16;
        int within = ncol - mat * 768;
        int head = within >> 6, dd = within & 63;
        float bias = bm[within] * bscale;
        #pragma unroll
        for (int rt = 0; rt < 4; rt++) {
            int sb = m0 + rt * 16 + quad * 4;
            if (mat == 2) {
                short4v pv;
                #pragma unroll
                for (int r = 0; r < 4; r++) pv[r] = (short)f2bf(acc[rt][ct][r] + bias);
                *(short4v*)(v_ws + head * (HD * SEQ) + dd * SEQ + sb) = pv;
            } else {
                unsigned short* dst = (mat == 0 ? q_ws : k_ws) + head * (SEQ * HD) + sb * HD + dd;
                #pragma unroll
                for (int r = 0; r < 4; r++)
                    dst[r * HD] = f2bf(acc[rt][ct][r] + bias);
            }
        }
    }
}

// ---------------- Banded attention: scores in registers, flash-style reduction ----------------
// grid 3072 (XCD-swizzled). 16 query rows/WG. Each wave owns column tiles {wave+4i}.
// LDS: bf16 probs + fm + 2 reduce buffers == ~20.4 KB -> 7-8 WGs/CU.
__global__ __launch_bounds__(256) void attn_kernel(
    const unsigned short* __restrict__ q_ws,
    const unsigned short* __restrict__ k_ws,
    const unsigned short* __restrict__ v_ws,
    const float* __restrict__ amask,
    const unsigned char* __restrict__ imask,
    float* __restrict__ out)
{
    const int lbid = blockIdx.x + gridDim.x * blockIdx.y;
    const int xcd = lbid & 7, slot = lbid >> 3;
    const int w = xcd * 384 + slot;
    const int h = w >> 8, c = w & 255;
    const int i0 = c * 16;
    const int j0 = i0 - 256;
    const int t = threadIdx.x;
    const int wave = t >> 6, lane = t & 63;
    const int quad = lane >> 4, l16 = lane & 15;

    __shared__ unsigned short Pb[16 * PSTR];  // bf16 probs, 17.5 KB
    __shared__ float fm[544];                 // per-key mask (log2 domain)
    __shared__ float redA[16][4];             // cross-wave max
    __shared__ float redB[16][4];             // cross-wave sum

    // fm fill + Pb tail zero (cols 528..543)
    for (int cc = t; cc < 544; cc += 256) {
        int j = j0 + cc;
        fm[cc] = (j < 0 || j >= SEQ) ? -1e30f : ((amask[j] != 0.0f) ? LNEG * LOG2E : 0.0f);
    }
    Pb[(t >> 4) * PSTR + 528 + (t & 15)] = 0;

    // Q fragments (log2e-scaled at prep); all waves hold the same 16 rows
    const unsigned short* qbase = q_ws + h * (SEQ * HD) + (i0 + l16) * HD + quad * 8;
    short8 a0 = *(const short8*)qbase;
    short8 a1 = *(const short8*)(qbase + 32);

    // ---- QK^T into registers: this wave's tiles {wave+4i, i<9} ----
    f32x4 sc[9];
    const unsigned short* kh = k_ws + h * (SEQ * HD);
    #pragma unroll
    for (int i = 0; i < 9; i++) {
        int tile = wave + 4 * i;
        if (tile < 33) {
            int j = j0 + tile * 16 + l16;
            int jc = min(max(j, 0), SEQ - 1);
            const unsigned short* kb = kh + jc * HD + quad * 8;
            short8 b0 = *(const short8*)kb;
            short8 b1 = *(const short8*)(kb + 32);
            f32x4 s = {0.f, 0.f, 0.f, 0.f};
            s = __builtin_amdgcn_mfma_f32_16x16x32_bf16(a0, b0, s, 0, 0, 0);
            s = __builtin_amdgcn_mfma_f32_16x16x32_bf16(a1, b1, s, 0, 0, 0);
            sc[i] = s;
        }
    }
    __syncthreads();   // fm / Pb-tail visible

    // ---- mask + per-row max (rows quad*4+x live in lanes sharing quad) ----
    f32x4 mx4 = {-1e30f, -1e30f, -1e30f, -1e30f};
    #pragma unroll
    for (int i = 0; i < 9; i++) {
        int tile = wave + 4 * i;
        if (tile < 33) {
            int cc = tile * 16 + l16;
            float fmv = fm[cc];
            #pragma unroll
            for (int x = 0; x < 4; x++) {
                int row = quad * 4 + x;
                float m = ((unsigned)(cc - row) <= 512u) ? (sc[i][x] + fmv) : -1e30f;
                sc[i][x] = m;
                mx4[x] = fmaxf(mx4[x], m);
            }
        }
    }
    #pragma unroll
    for (int off = 1; off < 16; off <<= 1)
        #pragma unroll
        for (int x = 0; x < 4; x++)
            mx4[x] = fmaxf(mx4[x], __shfl_xor(mx4[x], off));
    if (l16 == 0) {
        #pragma unroll
        for (int x = 0; x < 4; x++) redA[quad * 4 + x][wave] = mx4[x];
    }
    __syncthreads();

    f32x4 gmx;
    #pragma unroll
    for (int x = 0; x < 4; x++) {
        const float* rr = redA[quad * 4 + x];
        gmx[x] = fmaxf(fmaxf(rr[0], rr[1]), fmaxf(rr[2], rr[3]));
    }

    // ---- exp2 + per-row sum ----
    f32x4 sum4 = {0.f, 0.f, 0.f, 0.f};
    #pragma unroll
    for (int i = 0; i < 9; i++) {
        int tile = wave + 4 * i;
        if (tile < 33) {
            #pragma unroll
            for (int x = 0; x < 4; x++) {
                float e = exp2f(sc[i][x] - gmx[x]);
                sc[i][x] = e;
                sum4[x] += e;
            }
        }
    }
    #pragma unroll
    for (int off = 1; off < 16; off <<= 1)
        #pragma unroll
        for (int x = 0; x < 4; x++)
            sum4[x] += __shfl_xor(sum4[x], off);
    if (l16 == 0) {
        #pragma unroll
        for (int x = 0; x < 4; x++) redB[quad * 4 + x][wave] = sum4[x];
    }
    __syncthreads();

    f32x4 rinv;
    #pragma unroll
    for (int x = 0; x < 4; x++) {
        const float* rr = redB[quad * 4 + x];
        float tot = rr[0] + rr[1] + rr[2] + rr[3];
        rinv[x] = (imask[i0 + quad * 4 + x] != 0) ? 0.f : (1.f / tot);
    }

    // ---- normalize + bf16 -> Pb ----
    #pragma unroll
    for (int i = 0; i < 9; i++) {
        int tile = wave + 4 * i;
        if (tile < 33) {
            int cc = tile * 16 + l16;
            #pragma unroll
            for (int x = 0; x < 4; x++)
                Pb[(quad * 4 + x) * PSTR + cc] = f2bf(sc[i][x] * rinv[x]);
        }
    }
    __syncthreads();

    // ---- PV: each wave one 16-wide d tile, 17 K-groups of 32 ----
    f32x4 o = {0.f, 0.f, 0.f, 0.f};
    const int dd = wave * 16 + l16;
    const unsigned short* vbase = v_ws + h * (HD * SEQ) + dd * SEQ;
    for (int kk = 0; kk < 17; kk++) {
        short8 af = *(const short8*)(Pb + l16 * PSTR + kk * 32 + quad * 8);
        int jb = j0 + kk * 32 + quad * 8;
        jb = min(max(jb, 0), SEQ - 8);
        short8 vb = *(const short8*)(vbase + jb);
        o = __builtin_amdgcn_mfma_f32_16x16x32_bf16(af, vb, o, 0, 0, 0);
    }
    float* obase = out + (size_t)(i0 + quad * 4) * EMB + h * HD + dd;
    #pragma unroll
    for (int r = 0; r < 4; r++)
        obase[r * EMB] = o[r];
}

extern "C" void kernel_launch(void* const* d_in, const int* in_sizes, int n_in,
                              void* d_out, int out_size, void* d_ws, size_t ws_size,
                              hipStream_t stream) {
    (void)in_sizes; (void)n_in; (void)out_size; (void)ws_size;
    const float* hid = (const float*)d_in[0];
    const float* am  = (const float*)d_in[1];
    const unsigned char* im = (const unsigned char*)d_in[2];
    const float* Wq = (const float*)d_in[3];
    const float* bq = (const float*)d_in[4];
    const float* Wk = (const float*)d_in[5];
    const float* bk = (const float*)d_in[6];
    const float* Wv = (const float*)d_in[7];
    const float* bv = (const float*)d_in[8];
    float* out = (float*)d_out;

    unsigned short* ws = (unsigned short*)d_ws;
    unsigned short* q_ws = ws;
    unsigned short* k_ws = ws + (size_t)NH * SEQ * HD;
    unsigned short* v_ws = ws + 2 * (size_t)NH * SEQ * HD;
    unsigned short* hidb = (unsigned short*)d_out;   // d_out as scratch (attn overwrites last)
    unsigned short* Wt   = hidb + (size_t)SEQ * EMB;

    dim3 gp(12, 12, 4);
    prep_kernel<<<gp, 256, 0, stream>>>(hid, Wq, Wk, Wv, hidb, Wt);
    dim3 gg(64, 18);
    gemm_kernel<<<gg, 256, 0, stream>>>(hidb, Wt, bq, bk, bv, q_ws, k_ws, v_ws);
    dim3 ga(256, NH);
    attn_kernel<<<ga, 256, 0, stream>>>(q_ws, k_ws, v_ws, am, im, out);
}

// Round 5
// 160.196 us; speedup vs baseline: 1.6681x; 1.0634x over previous
//
#include <hip/hip_runtime.h>

#define SEQ 4096
#define EMB 768
#define NH 12
#define HD 64
#define KDIM 768
#define LNEG -100000000.0f
#define LOG2E 1.44269504f
#define PSTR 548   // Pb row stride (shorts): verified 0 conflicts in R4

typedef __attribute__((ext_vector_type(8))) short short8;
typedef __attribute__((ext_vector_type(4))) short short4v;
typedef __attribute__((ext_vector_type(4))) float f32x4;

__device__ inline unsigned short f2bf(float f) {
    unsigned int u = __float_as_uint(f);
    u += 0x7fffu + ((u >> 16) & 1u);
    return (unsigned short)(u >> 16);
}
__device__ inline float bf2f(unsigned short s) {
    unsigned int u = ((unsigned int)s) << 16;
    return __uint_as_float(u);
}

__device__ inline void gload_lds16(const unsigned short* g, unsigned short* l) {
    __builtin_amdgcn_global_load_lds(
        (const __attribute__((address_space(1))) void*)g,
        (__attribute__((address_space(3))) void*)l, 16, 0, 0);
}

// ---------------- Prep: hid -> bf16, W -> W^T bf16 (q-scale*log2e folded into Wq) ----------------
// grid 1008 linear: WGs 0..431 = W transpose tiles (3 mats x 144), 432..1007 = hid convert.
__global__ __launch_bounds__(256) void prep_kernel(
    const float* __restrict__ hid,
    const float* __restrict__ Wq, const float* __restrict__ Wk, const float* __restrict__ Wv,
    unsigned short* __restrict__ hidb,   // [4096][768] bf16
    unsigned short* __restrict__ Wt)     // [2304][768] bf16, [n][k]
{
    const int bid = blockIdx.x;
    const int t = threadIdx.x;
    if (bid >= 432) {
        int vid = (bid - 432) * 256 + t;
        const int nch = SEQ * EMB / 4;           // 196608 f32x4 chunks
        const int stride = 576 * 256;
        for (int c = vid; c < nch; c += stride) {
            f32x4 v = ((const f32x4*)hid)[c];
            short4v o;
            #pragma unroll
            for (int x = 0; x < 4; x++) o[x] = (short)f2bf(v[x]);
            ((short4v*)hidb)[c] = o;
        }
        return;
    }
    const int mat = bid / 144;
    const int r2 = bid % 144;
    const int k0 = (r2 % 12) * 64;
    const int n0 = (r2 / 12) * 64;
    const float* Wm = (mat == 0) ? Wq : (mat == 1 ? Wk : Wv);
    const float scale = (mat == 0) ? 0.125f * LOG2E : 1.0f;
    __shared__ unsigned short Lt[64 * 82];
    #pragma unroll
    for (int i = 0; i < 4; i++) {
        int row = i * 16 + (t >> 4);
        int col = (t & 15) * 4;
        f32x4 v = *(const f32x4*)(Wm + (size_t)(k0 + row) * EMB + n0 + col);
        #pragma unroll
        for (int x = 0; x < 4; x++)
            Lt[(col + x) * 82 + row] = f2bf(v[x] * scale);
    }
    __syncthreads();
    #pragma unroll
    for (int j = 0; j < 2; j++) {
        int idx = j * 256 + t;
        int nr = idx >> 3;
        int kc = (idx & 7) * 8;
        short8 o = *(const short8*)(Lt + nr * 82 + kc);
        *(short8*)(Wt + (size_t)(mat * 768 + n0 + nr) * KDIM + k0 + kc) = o;
    }
}

// ---------------- GEMM: 64x128 tiles, grid (64,18); LDS-bounce coalesced epilogue ----------------
__global__ __launch_bounds__(256) void gemm_kernel(
    const unsigned short* __restrict__ hidb,
    const unsigned short* __restrict__ Wt,
    const float* __restrict__ bq, const float* __restrict__ bk, const float* __restrict__ bv,
    unsigned short* __restrict__ q_ws,   // [H][S][D] bf16
    unsigned short* __restrict__ k_ws,   // [H][S][D] bf16
    unsigned short* __restrict__ v_ws)   // [H][D][S] bf16
{
    const int m0 = blockIdx.x * 64;
    const int n0 = blockIdx.y * 128;
    __shared__ union {
        struct { unsigned short Al[64 * 64]; unsigned short Bl[128 * 64]; } s;  // 24 KB
        unsigned short Cqk[64 * 140];   // 17.9 KB, stride 140 (280B, 8B-aligned rows)
        unsigned short Cv[128 * 72];    // 18.4 KB, stride 72 (144B, 16B-aligned rows)
    } sm;
    const int t = threadIdx.x;
    const int wave = t >> 6, lane = t & 63;
    const int quad = lane >> 4, l16 = lane & 15;

    const f32x4 zero = {0.f, 0.f, 0.f, 0.f};
    f32x4 acc[4][2];
    #pragma unroll
    for (int i = 0; i < 4; i++)
        #pragma unroll
        for (int j = 0; j < 2; j++) acc[i][j] = zero;

    for (int k0 = 0; k0 < KDIM; k0 += 64) {
        #pragma unroll
        for (int i = 0; i < 2; i++) {
            int c = (wave * 2 + i) * 64 + lane;
            int row = c >> 3;
            int kc = ((c & 7) ^ (row & 7)) * 8;
            gload_lds16(hidb + (size_t)(m0 + row) * KDIM + k0 + kc, sm.s.Al + (wave * 2 + i) * 512);
        }
        #pragma unroll
        for (int i = 0; i < 4; i++) {
            int c = (wave * 4 + i) * 64 + lane;
            int row = c >> 3;
            int kc = ((c & 7) ^ (row & 7)) * 8;
            gload_lds16(Wt + (size_t)(n0 + row) * KDIM + k0 + kc, sm.s.Bl + (wave * 4 + i) * 512);
        }
        __syncthreads();

        short8 af[2][4], bfr[2][2];
        #pragma unroll
        for (int rt = 0; rt < 4; rt++) {
            int rowA = rt * 16 + l16;
            #pragma unroll
            for (int s = 0; s < 2; s++)
                af[s][rt] = *(const short8*)(sm.s.Al + rowA * 64 + (((s << 2) | quad) ^ (rowA & 7)) * 8);
        }
        #pragma unroll
        for (int ct = 0; ct < 2; ct++) {
            int rowB = wave * 32 + ct * 16 + l16;
            #pragma unroll
            for (int s = 0; s < 2; s++)
                bfr[s][ct] = *(const short8*)(sm.s.Bl + rowB * 64 + (((s << 2) | quad) ^ (rowB & 7)) * 8);
        }
        #pragma unroll
        for (int s = 0; s < 2; s++)
            #pragma unroll
            for (int rt = 0; rt < 4; rt++)
                #pragma unroll
                for (int ct = 0; ct < 2; ct++)
                    acc[rt][ct] = __builtin_amdgcn_mfma_f32_16x16x32_bf16(af[s][rt], bfr[s][ct], acc[rt][ct], 0, 0, 0);
        __syncthreads();
    }

    const int mat = blockIdx.y / 6;
    const float* bm = (mat == 0) ? bq : (mat == 1 ? bk : bv);
    const float bscale = (mat == 0) ? 0.125f * LOG2E : 1.0f;

    if (mat != 2) {
        // dump acc -> Cqk[row_m][col_n], then coalesced 16B stores along d
        #pragma unroll
        for (int ct = 0; ct < 2; ct++) {
            int nloc = wave * 32 + ct * 16 + l16;
            float bias = bm[(n0 + nloc) - mat * 768] * bscale;
            #pragma unroll
            for (int rt = 0; rt < 4; rt++)
                #pragma unroll
                for (int r = 0; r < 4; r++)
                    sm.Cqk[(rt * 16 + quad * 4 + r) * 140 + nloc] = f2bf(acc[rt][ct][r] + bias);
        }
        __syncthreads();
        unsigned short* dst_ws = (mat == 0) ? q_ws : k_ws;
        #pragma unroll
        for (int p = 0; p < 4; p++) {
            int id = p * 256 + t;            // 1024 segments
            int row = id >> 4;               // 0..63 (m-local)
            int nloc = (id & 15) * 8;        // 0..120
            // rows are 8B-aligned: read as two b64
            long2 raw;
            ((long*)&raw)[0] = *(const long*)(sm.Cqk + row * 140 + nloc);
            ((long*)&raw)[1] = *(const long*)(sm.Cqk + row * 140 + nloc + 4);
            int within = (n0 + nloc) - mat * 768;
            int head = within >> 6, dd = within & 63;
            *(long2*)(dst_ws + (size_t)head * (SEQ * HD) + (size_t)(m0 + row) * HD + dd) = raw;
        }
    } else {
        // dump acc transposed -> Cv[col_n][row_m], then coalesced 16B stores along s
        #pragma unroll
        for (int ct = 0; ct < 2; ct++) {
            int nloc = wave * 32 + ct * 16 + l16;
            float bias = bm[(n0 + nloc) - 1536];
            #pragma unroll
            for (int rt = 0; rt < 4; rt++)
                #pragma unroll
                for (int r = 0; r < 4; r++)
                    sm.Cv[nloc * 72 + rt * 16 + quad * 4 + r] = f2bf(acc[rt][ct][r] + bias);
        }
        __syncthreads();
        #pragma unroll
        for (int p = 0; p < 4; p++) {
            int id = p * 256 + t;            // 1024 segments
            int ddl = id >> 3;               // 0..127 (n-local)
            int sseg = (id & 7) * 8;         // 0..56  (m-local, 8-chunks)
            short8 val = *(const short8*)(sm.Cv + ddl * 72 + sseg);
            int within = (n0 + ddl) - 1536;
            int head = within >> 6, dd = within & 63;
            *(short8*)(v_ws + (size_t)head * (HD * SEQ) + (size_t)dd * SEQ + m0 + sseg) = val;
        }
    }
}

// ---------------- Banded attention: single-pass softmax, deferred normalization ----------------
// grid 3072 (XCD-swizzled). 16 query rows/WG, window 528 (+16 pad -> 544). 2 barriers.
// No max subtraction: scores bounded (|s| << 80), exp2 direct. Pb holds UNNORMALIZED
// bf16 probs; 1/sum applied at output write (sum reduced across waves via redB).
__global__ __launch_bounds__(256) void attn_kernel(
    const unsigned short* __restrict__ q_ws,
    const unsigned short* __restrict__ k_ws,
    const unsigned short* __restrict__ v_ws,
    const float* __restrict__ amask,
    const unsigned char* __restrict__ imask,
    float* __restrict__ out)
{
    const int lbid = blockIdx.x;
    const int xcd = lbid & 7, slot = lbid >> 3;
    const int w = xcd * 384 + slot;
    const int h = w >> 8, c = w & 255;
    const int i0 = c * 16;
    const int j0 = i0 - 256;
    const int t = threadIdx.x;
    const int wave = t >> 6, lane = t & 63;
    const int quad = lane >> 4, l16 = lane & 15;
    const bool interior = (j0 >= 0) && (j0 + 544 <= SEQ);

    __shared__ unsigned short Pb[16 * PSTR];  // unnormalized bf16 probs
    __shared__ float fm[544];                 // per-key mask (log2 domain)
    __shared__ float redB[16][4];             // cross-wave sum partials

    // early loads: imask for this lane's 4 output rows
    unsigned char imv[4];
    #pragma unroll
    for (int x = 0; x < 4; x++) imv[x] = imask[i0 + quad * 4 + x];

    for (int cc = t; cc < 544; cc += 256) {
        int j = j0 + cc;
        float f;
        if (interior)
            f = (amask[j] != 0.0f) ? LNEG * LOG2E : 0.0f;
        else
            f = (j < 0 || j >= SEQ) ? -1e30f : ((amask[j] != 0.0f) ? LNEG * LOG2E : 0.0f);
        fm[cc] = f;
    }
    Pb[(t >> 4) * PSTR + 528 + (t & 15)] = 0;   // zero pad cols 528..543

    const unsigned short* qbase = q_ws + h * (SEQ * HD) + (i0 + l16) * HD + quad * 8;
    short8 a0 = *(const short8*)qbase;
    short8 a1 = *(const short8*)(qbase + 32);

    // ---- QK^T into registers: this wave's tiles {wave+4i} ----
    f32x4 sc[9];
    const unsigned short* kh = k_ws + h * (SEQ * HD);
    if (interior) {
        #pragma unroll
        for (int i = 0; i < 9; i++) {
            int tile = wave + 4 * i;
            if (tile < 33) {
                const unsigned short* kb = kh + (size_t)(j0 + tile * 16 + l16) * HD + quad * 8;
                short8 b0 = *(const short8*)kb;
                short8 b1 = *(const short8*)(kb + 32);
                f32x4 s = {0.f, 0.f, 0.f, 0.f};
                s = __builtin_amdgcn_mfma_f32_16x16x32_bf16(a0, b0, s, 0, 0, 0);
                s = __builtin_amdgcn_mfma_f32_16x16x32_bf16(a1, b1, s, 0, 0, 0);
                sc[i] = s;
            }
        }
    } else {
        #pragma unroll
        for (int i = 0; i < 9; i++) {
            int tile = wave + 4 * i;
            if (tile < 33) {
                int j = j0 + tile * 16 + l16;
                int jc = min(max(j, 0), SEQ - 1);
                const unsigned short* kb = kh + (size_t)jc * HD + quad * 8;
                short8 b0 = *(const short8*)kb;
                short8 b1 = *(const short8*)(kb + 32);
                f32x4 s = {0.f, 0.f, 0.f, 0.f};
                s = __builtin_amdgcn_mfma_f32_16x16x32_bf16(a0, b0, s, 0, 0, 0);
                s = __builtin_amdgcn_mfma_f32_16x16x32_bf16(a1, b1, s, 0, 0, 0);
                sc[i] = s;
            }
        }
    }
    __syncthreads();   // fm / Pb-tail visible

    // ---- single pass: mask + exp2 + bf16 store + row-sum ----
    f32x4 sum4 = {0.f, 0.f, 0.f, 0.f};
    #pragma unroll
    for (int i = 0; i < 9; i++) {
        int tile = wave + 4 * i;
        if (tile < 33) {
            int cc = tile * 16 + l16;
            float fmv = fm[cc];
            #pragma unroll
            for (int x = 0; x < 4; x++) {
                int row = quad * 4 + x;
                float e = ((unsigned)(cc - row) <= 512u)
                              ? __builtin_amdgcn_exp2f(sc[i][x] + fmv) : 0.f;
                unsigned short pb = f2bf(e);
                Pb[row * PSTR + cc] = pb;
                sum4[x] += bf2f(pb);      // sum the rounded value (matches PV operand)
            }
        }
    }
    #pragma unroll
    for (int off = 1; off < 16; off <<= 1)
        #pragma unroll
        for (int x = 0; x < 4; x++)
            sum4[x] += __shfl_xor(sum4[x], off);
    if (l16 == 0) {
        #pragma unroll
        for (int x = 0; x < 4; x++) redB[quad * 4 + x][wave] = sum4[x];
    }
    __syncthreads();

    // ---- PV on unnormalized probs ----
    f32x4 o = {0.f, 0.f, 0.f, 0.f};
    const int dd = wave * 16 + l16;
    const unsigned short* vbase = v_ws + h * (HD * SEQ) + dd * SEQ;
    if (interior) {
        #pragma unroll
        for (int kk = 0; kk < 17; kk++) {
            short8 af = *(const short8*)(Pb + l16 * PSTR + kk * 32 + quad * 8);
            short8 vb = *(const short8*)(vbase + j0 + kk * 32 + quad * 8);
            o = __builtin_amdgcn_mfma_f32_16x16x32_bf16(af, vb, o, 0, 0, 0);
        }
    } else {
        #pragma unroll
        for (int kk = 0; kk < 17; kk++) {
            short8 af = *(const short8*)(Pb + l16 * PSTR + kk * 32 + quad * 8);
            int jb = j0 + kk * 32 + quad * 8;
            jb = min(max(jb, 0), SEQ - 8);
            short8 vb = *(const short8*)(vbase + jb);
            o = __builtin_amdgcn_mfma_f32_16x16x32_bf16(af, vb, o, 0, 0, 0);
        }
    }

    // ---- scale by 1/sum (+ imask) and store ----
    float* obase = out + (size_t)(i0 + quad * 4) * EMB + h * HD + dd;
    #pragma unroll
    for (int r = 0; r < 4; r++) {
        const float* rr = redB[quad * 4 + r];
        float tot = rr[0] + rr[1] + rr[2] + rr[3];
        float rinv = imv[r] ? 0.f : __builtin_amdgcn_rcpf(tot);
        obase[r * EMB] = o[r] * rinv;
    }
}

extern "C" void kernel_launch(void* const* d_in, const int* in_sizes, int n_in,
                              void* d_out, int out_size, void* d_ws, size_t ws_size,
                              hipStream_t stream) {
    (void)in_sizes; (void)n_in; (void)out_size; (void)ws_size;
    const float* hid = (const float*)d_in[0];
    const float* am  = (const float*)d_in[1];
    const unsigned char* im = (const unsigned char*)d_in[2];
    const float* Wq = (const float*)d_in[3];
    const float* bq = (const float*)d_in[4];
    const float* Wk = (const float*)d_in[5];
    const float* bk = (const float*)d_in[6];
    const float* Wv = (const float*)d_in[7];
    const float* bv = (const float*)d_in[8];
    float* out = (float*)d_out;

    unsigned short* ws = (unsigned short*)d_ws;
    unsigned short* q_ws = ws;
    unsigned short* k_ws = ws + (size_t)NH * SEQ * HD;
    unsigned short* v_ws = ws + 2 * (size_t)NH * SEQ * HD;
    unsigned short* hidb = (unsigned short*)d_out;   // d_out as scratch (attn overwrites last)
    unsigned short* Wt   = hidb + (size_t)SEQ * EMB;

    prep_kernel<<<dim3(1008), 256, 0, stream>>>(hid, Wq, Wk, Wv, hidb, Wt);
    gemm_kernel<<<dim3(64, 18), 256, 0, stream>>>(hidb, Wt, bq, bk, bv, q_ws, k_ws, v_ws);
    attn_kernel<<<dim3(3072), 256, 0, stream>>>(q_ws, k_ws, v_ws, am, im, out);
}